// Round 2
// baseline (4074.178 us; speedup 1.0000x reference)
//
#include <hip/hip_runtime.h>
#include <hip/hip_fp16.h>
#include <math.h>

// Shapes (fixed): B=2, H=16, L=8192, dh=64, D=1024, 3*INNER=3072, NPROJ=7,
// BLOCK=256, SAMPLE=256.  Workspace use ~140 MB (was 343 MB -> mem fault).

__device__ __forceinline__ void load16h(const __half* p, float* dst) {
    const __half2* h2 = (const __half2*)p;
#pragma unroll
    for (int i = 0; i < 8; ++i) {
        float2 f = __half22float2(h2[i]);
        dst[2 * i] = f.x; dst[2 * i + 1] = f.y;
    }
}
__device__ __forceinline__ void store16h(__half* p, const float* src) {
    __half2* h2 = (__half2*)p;
#pragma unroll
    for (int i = 0; i < 8; ++i)
        h2[i] = __floats2half2_rn(src[2 * i], src[2 * i + 1]);
}

// ---- fold: fold[(w*16+h)*7+r][i] = sum_d W[i, w*1024+h*64+d]*proj[d,r]  (fp64) ----
__global__ __launch_bounds__(256) void fold_kernel(
    const float* __restrict__ W, const float* __restrict__ bias,
    const float* __restrict__ proj, double* __restrict__ fold,
    double* __restrict__ bfold)
{
    int idx = blockIdx.x * 256 + threadIdx.x;
    if (idx < 2 * 16 * 7 * 1024) {
        int i = idx & 1023;
        int rem = idx >> 10;          // (w*16+h)*7 + r
        int r = rem % 7;
        int hr = rem / 7;             // w*16+h
        int h = hr & 15;
        int w = hr >> 4;
        double s = 0.0;
        const float* wp = W + (size_t)i * 3072 + w * 1024 + h * 64;
        for (int d = 0; d < 64; ++d)
            s += (double)wp[d] * (double)proj[d * 7 + r];
        fold[idx] = s;
    }
    if (idx < 224) {
        int r = idx % 7;
        int hr = idx / 7;
        int h = hr & 15;
        int w = hr >> 4;
        double s = 0.0;
        for (int d = 0; d < 64; ++d)
            s += (double)bias[w * 1024 + h * 64 + d] * (double)proj[d * 7 + r];
        bfold[idx] = s;
    }
}

// ---- hash: per (b,l) row, 32 tasks (w=q/k, h) -> gray-coded bucket id ----
__global__ __launch_bounds__(256) void hash_kernel(
    const float* __restrict__ x, const double* __restrict__ fold,
    const double* __restrict__ bfold, int* __restrict__ hq, int* __restrict__ hk)
{
    __shared__ float xs[1024];
    int bl = blockIdx.x;           // b*8192 + l
    int t = threadIdx.x;
    for (int i = t; i < 1024; i += 256) xs[i] = x[(size_t)bl * 1024 + i];
    __syncthreads();
    int lane = t & 63, wv = t >> 6;
    int b = bl >> 13, l = bl & 8191;
    for (int task = wv; task < 32; task += 4) {
        int w = task >> 4, h = task & 15;
        const double* f = fold + (size_t)task * 7 * 1024;
        double acc[7] = {0, 0, 0, 0, 0, 0, 0};
        for (int i = lane; i < 1024; i += 64) {
            double xv = (double)xs[i];
#pragma unroll
            for (int r = 0; r < 7; ++r) acc[r] += xv * f[(size_t)r * 1024 + i];
        }
        int id = 0;
#pragma unroll
        for (int r = 0; r < 7; ++r) {
            double a = acc[r];
#pragma unroll
            for (int off = 32; off > 0; off >>= 1) a += __shfl_down(a, off, 64);
            if (lane == 0) {
                double tot = a + bfold[task * 7 + r];
                if (tot > 0.0) id |= (1 << r);
            }
        }
        if (lane == 0) {
            int hsh = id ^ (id >> 1);   // _hamming_perm == binary-reflected gray code
            int* dst = (w == 0) ? hq : hk;
            dst[((size_t)(b * 16 + h) << 13) + l] = hsh;
        }
    }
}

// ---- stable counting sort (128 buckets) per (b,h): idx[pos] = orig_row ----
__global__ __launch_bounds__(256) void sort_kernel(
    const int* __restrict__ hq, const int* __restrict__ hk,
    int* __restrict__ qidx, int* __restrict__ kidx)
{
    __shared__ unsigned short cnt[128][128]; // [chunk][bucket]
    __shared__ int tot[128];
    __shared__ int base[128];
    int blk = blockIdx.x;
    int sel = blk >> 5, bh = blk & 31;
    const int* hp = (sel ? hk : hq) + ((size_t)bh << 13);
    int* op = (sel ? kidx : qidx) + ((size_t)bh << 13);
    int t = threadIdx.x;
    for (int i = t; i < 128 * 128 / 2; i += 256) ((unsigned int*)cnt)[i] = 0u;
    __syncthreads();
    if (t < 128) {
        const int* p = hp + t * 64;
        for (int j = 0; j < 64; ++j) cnt[t][p[j]]++;
    }
    __syncthreads();
    if (t < 128) {
        int run = 0;
        for (int c = 0; c < 128; ++c) {
            int x2 = cnt[c][t];
            cnt[c][t] = (unsigned short)run;
            run += x2;
        }
        tot[t] = run;
    }
    __syncthreads();
    if (t == 0) {
        int run = 0;
        for (int v = 0; v < 128; ++v) { base[v] = run; run += tot[v]; }
    }
    __syncthreads();
    if (t < 128) {
        const int* p = hp + t * 64;
        for (int j = 0; j < 64; ++j) {
            int v = p[j];
            int c = cnt[t][v];
            cnt[t][v] = (unsigned short)(c + 1);
            op[base[v] + c] = t * 64 + j;
        }
    }
}

// ---- fused attention: block-diagonal (256 keys) + sampled residual (256 keys,
// bias +log32, same-block masked) as ONE online softmax == reference LSE merge.
// grid (bh,qb)=1024 blocks x 256thr; thread: dg=t&3 (16-dim slice), qq=t>>2,
// queries qb*256+qq+64i.  Writes merged attn scattered to pre[b,orig,l h*64+d].
__global__ __launch_bounds__(256) void attn_kernel(
    const __half* __restrict__ q, const __half* __restrict__ k,
    const __half* __restrict__ v, const int* __restrict__ qidx,
    const int* __restrict__ kidx, const int* __restrict__ sampled,
    __half* __restrict__ pre)
{
    __shared__ float Ks[64][64];
    __shared__ float Vs[64][64];
    __shared__ int sblk[64];
    int bh = blockIdx.x >> 5, qb = blockIdx.x & 31;
    int bb = bh >> 4, hh = bh & 15;
    size_t hb = (size_t)bh << 13;
    int t = threadIdx.x;
    int dg = t & 3, qq = t >> 2;
    float qr[4][16], o[4][16], m[4], l[4];
    int origs[4];
#pragma unroll
    for (int i = 0; i < 4; ++i) {
        int s = qb * 256 + qq + 64 * i;
        int orig = qidx[hb + s];
        origs[i] = orig;
        load16h(q + (hb + orig) * 64 + dg * 16, qr[i]);
        m[i] = -1e30f; l[i] = 0.f;
#pragma unroll
        for (int w = 0; w < 16; ++w) o[i][w] = 0.f;
    }
    const float LOG32 = 3.4657359027997265f;   // log(L / SAMPLE)
    for (int kc = 0; kc < 8; ++kc) {
        bool samp = kc >= 4;
        __syncthreads();
        {
            int j = t >> 2, c0 = (t & 3) * 16;
            int p = samp ? sampled[(size_t)bh * 256 + (kc - 4) * 64 + j]
                         : qb * 256 + kc * 64 + j;
            if (c0 == 0) sblk[j] = samp ? (p >> 8) : -1;
            int kr = kidx[hb + p];
            float kt[16], vt[16];
            load16h(k + (hb + kr) * 64 + c0, kt);
            load16h(v + (hb + kr) * 64 + c0, vt);
#pragma unroll
            for (int w = 0; w < 16; ++w) { Ks[j][c0 + w] = kt[w]; Vs[j][c0 + w] = vt[w]; }
        }
        __syncthreads();
        float badd = samp ? LOG32 : 0.f;
#pragma unroll 2
        for (int j = 0; j < 64; ++j) {
            if (sblk[j] == qb) continue;   // masked sampled key (covered by block)
            float kv16[16], vv16[16];
#pragma unroll
            for (int w = 0; w < 16; ++w) kv16[w] = Ks[j][dg * 16 + w];
#pragma unroll
            for (int w = 0; w < 16; ++w) vv16[w] = Vs[j][dg * 16 + w];
#pragma unroll
            for (int i = 0; i < 4; ++i) {
                float pp = 0.f;
#pragma unroll
                for (int w = 0; w < 16; ++w) pp += qr[i][w] * kv16[w];
                pp += __shfl_xor(pp, 1, 64);
                pp += __shfl_xor(pp, 2, 64);   // 4 dg lanes now hold full 64-dim dot
                float sc = pp * 0.125f + badd;
                if (sc <= m[i]) {
                    float wg = __expf(sc - m[i]);
                    l[i] += wg;
#pragma unroll
                    for (int w = 0; w < 16; ++w) o[i][w] += wg * vv16[w];
                } else {
                    float fq = __expf(m[i] - sc);
                    m[i] = sc;
                    l[i] = l[i] * fq + 1.f;
#pragma unroll
                    for (int w = 0; w < 16; ++w) o[i][w] = o[i][w] * fq + vv16[w];
                }
            }
        }
    }
#pragma unroll
    for (int i = 0; i < 4; ++i) {
        float invl = 1.f / l[i];
        float res[16];
#pragma unroll
        for (int w = 0; w < 16; ++w) res[w] = o[i][w] * invl;
        store16h(pre + ((size_t)(bb * 8192 + origs[i]) * 1024) + hh * 64 + dg * 16, res);
    }
}

// ---- QKV GEMM: fp32 A[16384,1024] x B[1024,3072], scatter +bias -> q/k/v f16 ----
__global__ __launch_bounds__(256) void gemm_qkv_kernel(
    const float* __restrict__ A, const float* __restrict__ Bm,
    const float* __restrict__ bias, __half* __restrict__ Q,
    __half* __restrict__ Kb, __half* __restrict__ Vb)
{
    const int N = 3072, K = 1024;
    __shared__ float As[8][128];
    __shared__ float Bs[8][128];
    int t = threadIdx.x;
    int bx = blockIdx.x, by = blockIdx.y;
    int tx = t & 15, ty = t >> 4;
    int ar = t >> 1, ac = (t & 1) * 4;
    int br = t >> 5, bc = (t & 31) * 4;
    const float* Ap = A + (size_t)(by * 128 + ar) * K + ac;
    const float* Bp = Bm + (size_t)br * N + bx * 128 + bc;
    float acc[8][8];
#pragma unroll
    for (int i = 0; i < 8; ++i)
#pragma unroll
        for (int j = 0; j < 8; ++j) acc[i][j] = 0.f;
    for (int kt = 0; kt < K; kt += 8) {
        float4 av = *(const float4*)(Ap + kt);
        float4 bv = *(const float4*)(Bp + (size_t)kt * N);
        __syncthreads();
        As[ac + 0][ar] = av.x; As[ac + 1][ar] = av.y;
        As[ac + 2][ar] = av.z; As[ac + 3][ar] = av.w;
        *(float4*)&Bs[br][bc] = bv;
        __syncthreads();
#pragma unroll
        for (int kk = 0; kk < 8; ++kk) {
            float a[8], b[8];
            *(float4*)(a)     = *(const float4*)&As[kk][ty * 4];
            *(float4*)(a + 4) = *(const float4*)&As[kk][64 + ty * 4];
            *(float4*)(b)     = *(const float4*)&Bs[kk][tx * 4];
            *(float4*)(b + 4) = *(const float4*)&Bs[kk][64 + tx * 4];
#pragma unroll
            for (int i = 0; i < 8; ++i)
#pragma unroll
                for (int j = 0; j < 8; ++j) acc[i][j] = fmaf(a[i], b[j], acc[i][j]);
        }
    }
#pragma unroll
    for (int i = 0; i < 8; ++i) {
        int gm = by * 128 + (i < 4 ? ty * 4 + i : 64 + ty * 4 + (i - 4));
#pragma unroll
        for (int j = 0; j < 8; ++j) {
            int gn = bx * 128 + (j < 4 ? tx * 4 + j : 64 + tx * 4 + (j - 4));
            float val = acc[i][j] + bias[gn];
            int s = gn >> 10, h = (gn >> 6) & 15, d = gn & 63;
            int b2 = gm >> 13, ll = gm & 8191;
            __half* dst = (s == 0) ? Q : (s == 1 ? Kb : Vb);
            dst[(((size_t)(b2 * 16 + h) << 13) + ll) * 64 + d] = __float2half_rn(val);
        }
    }
}

// ---- OUT GEMM: f16 A[16384,1024] x fp32 B[1024,1024] + bias -> fp32 out ----
__global__ __launch_bounds__(256) void gemm_out_kernel(
    const __half* __restrict__ A, const float* __restrict__ Bm,
    const float* __restrict__ bias, float* __restrict__ C)
{
    const int N = 1024, K = 1024;
    __shared__ float As[8][128];
    __shared__ float Bs[8][128];
    int t = threadIdx.x;
    int bx = blockIdx.x, by = blockIdx.y;
    int tx = t & 15, ty = t >> 4;
    int ar = t >> 1, ac = (t & 1) * 4;
    int br = t >> 5, bc = (t & 31) * 4;
    const __half* Ap = A + (size_t)(by * 128 + ar) * K + ac;
    const float* Bp = Bm + (size_t)br * N + bx * 128 + bc;
    float acc[8][8];
#pragma unroll
    for (int i = 0; i < 8; ++i)
#pragma unroll
        for (int j = 0; j < 8; ++j) acc[i][j] = 0.f;
    for (int kt = 0; kt < K; kt += 8) {
        __half2 h0 = *(const __half2*)(Ap + kt);
        __half2 h1 = *(const __half2*)(Ap + kt + 2);
        float4 bv = *(const float4*)(Bp + (size_t)kt * N);
        float2 f0 = __half22float2(h0), f1 = __half22float2(h1);
        __syncthreads();
        As[ac + 0][ar] = f0.x; As[ac + 1][ar] = f0.y;
        As[ac + 2][ar] = f1.x; As[ac + 3][ar] = f1.y;
        *(float4*)&Bs[br][bc] = bv;
        __syncthreads();
#pragma unroll
        for (int kk = 0; kk < 8; ++kk) {
            float a[8], b[8];
            *(float4*)(a)     = *(const float4*)&As[kk][ty * 4];
            *(float4*)(a + 4) = *(const float4*)&As[kk][64 + ty * 4];
            *(float4*)(b)     = *(const float4*)&Bs[kk][tx * 4];
            *(float4*)(b + 4) = *(const float4*)&Bs[kk][64 + tx * 4];
#pragma unroll
            for (int i = 0; i < 8; ++i)
#pragma unroll
                for (int j = 0; j < 8; ++j) acc[i][j] = fmaf(a[i], b[j], acc[i][j]);
        }
    }
#pragma unroll
    for (int i = 0; i < 8; ++i) {
        int gm = by * 128 + (i < 4 ? ty * 4 + i : 64 + ty * 4 + (i - 4));
#pragma unroll
        for (int j = 0; j < 8; ++j) {
            int gn = bx * 128 + (j < 4 ? tx * 4 + j : 64 + tx * 4 + (j - 4));
            C[(size_t)gm * N + gn] = acc[i][j] + bias[gn];
        }
    }
}

extern "C" void kernel_launch(void* const* d_in, const int* in_sizes, int n_in,
                              void* d_out, int out_size, void* d_ws, size_t ws_size,
                              hipStream_t stream)
{
    (void)in_sizes; (void)n_in; (void)out_size; (void)ws_size;
    const float* x     = (const float*)d_in[0];
    const float* Wqkv  = (const float*)d_in[1];
    const float* bqkv  = (const float*)d_in[2];
    const float* Wproj = (const float*)d_in[3];
    const float* bproj = (const float*)d_in[4];
    const float* proj  = (const float*)d_in[5];
    const int*   samp  = (const int*)d_in[6];
    float* out = (float*)d_out;

    char* ws = (char*)d_ws;
    size_t off = 0;
    auto take = [&](size_t bytes) {
        char* p = ws + off;
        off = (off + bytes + 255) & ~(size_t)255;
        return p;
    };
    __half* q   = (__half*)take(33554432);   // [B,H,L,64] f16
    __half* k   = (__half*)take(33554432);
    __half* v   = (__half*)take(33554432);
    __half* pre = (__half*)take(33554432);   // merged attn, un-sorted, [B,L,1024] f16
    double* fold  = (double*)take((size_t)2 * 16 * 7 * 1024 * 8);
    double* bfold = (double*)take(224 * 8);
    int* hq   = (int*)take(1048576);
    int* hk   = (int*)take(1048576);
    int* qidx = (int*)take(1048576);
    int* kidx = (int*)take(1048576);
    // total ~140.3 MB

    fold_kernel<<<dim3(896), dim3(256), 0, stream>>>(Wqkv, bqkv, proj, fold, bfold);
    hash_kernel<<<dim3(16384), dim3(256), 0, stream>>>(x, fold, bfold, hq, hk);
    sort_kernel<<<dim3(64), dim3(256), 0, stream>>>(hq, hk, qidx, kidx);
    gemm_qkv_kernel<<<dim3(24, 128), dim3(256), 0, stream>>>(x, Wqkv, bqkv, q, k, v);
    attn_kernel<<<dim3(1024), dim3(256), 0, stream>>>(q, k, v, qidx, kidx, samp, pre);
    gemm_out_kernel<<<dim3(8, 128), dim3(256), 0, stream>>>(pre, Wproj, bproj, out);
}

// Round 3
// 1697.879 us; speedup vs baseline: 2.3996x; 2.3996x over previous
//
#include <hip/hip_runtime.h>
#include <hip/hip_fp16.h>
#include <math.h>

// Shapes (fixed): B=2, H=16, L=8192, dh=64, D=1024, 3*INNER=3072, NPROJ=7,
// BLOCK=256, SAMPLE=256.

typedef _Float16 f16x8 __attribute__((ext_vector_type(8)));
typedef float f32x4 __attribute__((ext_vector_type(4)));

__device__ __forceinline__ void gl_lds16(const void* g, void* s) {
    __builtin_amdgcn_global_load_lds(
        (const __attribute__((address_space(1))) unsigned int*)g,
        (__attribute__((address_space(3))) unsigned int*)s, 16, 0, 0);
}

__device__ __forceinline__ void load16h(const __half* p, float* dst) {
    const __half2* h2 = (const __half2*)p;
#pragma unroll
    for (int i = 0; i < 8; ++i) {
        float2 f = __half22float2(h2[i]);
        dst[2 * i] = f.x; dst[2 * i + 1] = f.y;
    }
}
__device__ __forceinline__ void store16h(__half* p, const float* src) {
    __half2* h2 = (__half2*)p;
#pragma unroll
    for (int i = 0; i < 8; ++i)
        h2[i] = __floats2half2_rn(src[2 * i], src[2 * i + 1]);
}

// ---- fold: fold[task*7168 + i*7 + r] = sum_d W[i, w*1024+h*64+d]*proj[d,r] (fp64),
//      task = w*16+h.  k-major-with-r-contiguous so hash reads are s_load batches.
__global__ __launch_bounds__(256) void fold_kernel(
    const float* __restrict__ W, const float* __restrict__ bias,
    const float* __restrict__ proj, double* __restrict__ fold,
    double* __restrict__ bfold)
{
    int idx = blockIdx.x * 256 + threadIdx.x;
    if (idx < 2 * 16 * 7 * 1024) {
        int task = idx / 7168;
        int rem = idx - task * 7168;
        int i = rem / 7;
        int r = rem - i * 7;
        int h = task & 15, w = task >> 4;
        double s = 0.0;
        const float* wp = W + (size_t)i * 3072 + w * 1024 + h * 64;
        for (int d = 0; d < 64; ++d)
            s += (double)wp[d] * (double)proj[d * 7 + r];
        fold[idx] = s;
    }
    if (idx < 224) {    // bfold[task*7 + r]
        int r = idx % 7;
        int task = idx / 7;
        int h = task & 15, w = task >> 4;
        double s = 0.0;
        for (int d = 0; d < 64; ++d)
            s += (double)bias[w * 1024 + h * 64 + d] * (double)proj[d * 7 + r];
        bfold[idx] = s;
    }
}

// ---- hash: grid (task=32, rowblock=64); block = 256 rows x full K.
// x chunk staged in padded LDS; fold read wave-uniform (s_load path).
__global__ __launch_bounds__(256) void hash_kernel(
    const float* __restrict__ x, const double* __restrict__ fold,
    const double* __restrict__ bfold, int* __restrict__ hq, int* __restrict__ hk)
{
    __shared__ __align__(16) float Xs[256][66];
    int task = blockIdx.x;          // 0..31  (w*16+h)
    int gr0 = blockIdx.y * 256;     // global row base (b*8192+l flat)
    int t = threadIdx.x;
    const double* fbase = fold + (size_t)task * 7168;
    double acc[7] = {0, 0, 0, 0, 0, 0, 0};
    for (int c = 0; c < 16; ++c) {          // K chunks of 64
        __syncthreads();
        // stage 256 rows x 64 cols fp32 (coalesced float4 reads)
#pragma unroll
        for (int q2 = 0; q2 < 16; ++q2) {
            int fi = t + 256 * q2;
            int r2 = fi >> 4, c4 = fi & 15;
            float4 f = *(const float4*)&x[(size_t)(gr0 + r2) * 1024 + c * 64 + c4 * 4];
            *(float2*)&Xs[r2][c4 * 4] = make_float2(f.x, f.y);
            *(float2*)&Xs[r2][c4 * 4 + 2] = make_float2(f.z, f.w);
        }
        __syncthreads();
        const double* fc = fbase + c * 64 * 7;
#pragma unroll 4
        for (int i = 0; i < 64; ++i) {
            double xv = (double)Xs[t][i];
#pragma unroll
            for (int r = 0; r < 7; ++r)
                acc[r] = fma(xv, fc[i * 7 + r], acc[r]);
        }
    }
    int w = task >> 4, h = task & 15;
    int grow = gr0 + t;
    int b = grow >> 13, l = grow & 8191;
    int id = 0;
#pragma unroll
    for (int r = 0; r < 7; ++r)
        if (acc[r] + bfold[task * 7 + r] > 0.0) id |= (1 << r);
    int hsh = id ^ (id >> 1);   // _hamming_perm == binary-reflected gray code
    (w ? hk : hq)[((size_t)(b * 16 + h) << 13) + l] = hsh;
}

// ---- stable counting sort (128 buckets) per (b,h): idx[pos] = orig_row ----
__global__ __launch_bounds__(256) void sort_kernel(
    const int* __restrict__ hq, const int* __restrict__ hk,
    int* __restrict__ qidx, int* __restrict__ kidx)
{
    __shared__ unsigned short cnt[128][128];
    __shared__ int tot[128];
    __shared__ int base[128];
    int blk = blockIdx.x;
    int sel = blk >> 5, bh = blk & 31;
    const int* hp = (sel ? hk : hq) + ((size_t)bh << 13);
    int* op = (sel ? kidx : qidx) + ((size_t)bh << 13);
    int t = threadIdx.x;
    for (int i = t; i < 128 * 128 / 2; i += 256) ((unsigned int*)cnt)[i] = 0u;
    __syncthreads();
    if (t < 128) {
        const int* p = hp + t * 64;
        for (int j = 0; j < 64; ++j) cnt[t][p[j]]++;
    }
    __syncthreads();
    if (t < 128) {
        int run = 0;
        for (int c = 0; c < 128; ++c) {
            int x2 = cnt[c][t];
            cnt[c][t] = (unsigned short)run;
            run += x2;
        }
        tot[t] = run;
    }
    __syncthreads();
    if (t == 0) {
        int run = 0;
        for (int v = 0; v < 128; ++v) { base[v] = run; run += tot[v]; }
    }
    __syncthreads();
    if (t < 128) {
        const int* p = hp + t * 64;
        for (int j = 0; j < 64; ++j) {
            int v = p[j];
            int c = cnt[t][v];
            cnt[t][v] = (unsigned short)(c + 1);
            op[base[v] + c] = t * 64 + j;
        }
    }
}

// ---- cast x fp32 -> f16 ----
__global__ __launch_bounds__(256) void castx_kernel(
    const float* __restrict__ x, _Float16* __restrict__ xh)
{
    int i = blockIdx.x * 256 + threadIdx.x;   // over float4s, 4194304 total
    float4 f = ((const float4*)x)[i];
    f16x8 dummy;
    _Float16 h4[4] = {(_Float16)f.x, (_Float16)f.y, (_Float16)f.z, (_Float16)f.w};
    *(short4*)&xh[(size_t)i * 4] = *(short4*)h4;
    (void)dummy;
}

// ---- transpose+cast: W[K][N] fp32 -> Wt[N][K] f16 ----
__global__ __launch_bounds__(256) void transpose_kernel(
    const float* __restrict__ W, _Float16* __restrict__ Wt, int K, int N)
{
    __shared__ float tile[32][33];
    int bx = blockIdx.x, by = blockIdx.y;
    int tx = threadIdx.x & 31, ty = threadIdx.x >> 5;
    for (int i = ty; i < 32; i += 8)
        tile[i][tx] = W[(size_t)(by * 32 + i) * N + bx * 32 + tx];
    __syncthreads();
    for (int i = ty; i < 32; i += 8)
        Wt[(size_t)(bx * 32 + i) * K + by * 32 + tx] = (_Float16)tile[tx][i];
}

// ---- f16 MFMA GEMM, m97 structure: 128x128 tile, BK=32, 4 waves (2x2), 16x16x32.
// A [M][K] f16 row-major, Bt [N][K] f16 row-major (both contiguous-K).
// MODE 0: C[M][N] fp32 = A@Bt^T + bias.  MODE 1: scatter +bias -> q/k/v f16 [B,H,L,64].
template <int MODE>
__global__ __launch_bounds__(256) void mfma_gemm(
    const _Float16* __restrict__ A, const _Float16* __restrict__ Bt,
    const float* __restrict__ bias, float* __restrict__ C,
    __half* __restrict__ Q, __half* __restrict__ Kb, __half* __restrict__ Vb,
    int K, int N)
{
    __shared__ __align__(16) _Float16 As[128 * 32];
    __shared__ __align__(16) _Float16 Bs[128 * 32];
    int t = threadIdx.x;
    int w = t >> 6, l = t & 63;
    int m0 = blockIdx.y * 128, n0 = blockIdx.x * 128;
    // staging: wave w covers tile rows 32w..32w+31; lane l -> row 32w+(l>>2), slot l&3
    const _Float16* ga = A + (size_t)(m0 + 32 * w + (l >> 2)) * K + (l & 3) * 8;
    const _Float16* gb = Bt + (size_t)(n0 + 32 * w + (l >> 2)) * K + (l & 3) * 8;
    char* lasA = (char*)As + w * 2048;
    char* lasB = (char*)Bs + w * 2048;
    int wr = w >> 1, wc = w & 1;
    int rl = l & 15, ks = l >> 4;
    f32x4 acc[4][4];
#pragma unroll
    for (int m = 0; m < 4; ++m)
#pragma unroll
        for (int n = 0; n < 4; ++n) acc[m][n] = (f32x4){0.f, 0.f, 0.f, 0.f};
    for (int kk = 0; kk < K; kk += 32) {
        __syncthreads();
        gl_lds16(ga, lasA);
        gl_lds16(ga + 16 * K, lasA + 1024);
        gl_lds16(gb, lasB);
        gl_lds16(gb + 16 * K, lasB + 1024);
        ga += 32; gb += 32;
        __syncthreads();
        f16x8 af[4], bf[4];
#pragma unroll
        for (int m = 0; m < 4; ++m)
            af[m] = *(const f16x8*)((char*)As + (64 * wr + 16 * m + rl) * 64 + ks * 16);
#pragma unroll
        for (int n = 0; n < 4; ++n)
            bf[n] = *(const f16x8*)((char*)Bs + (64 * wc + 16 * n + rl) * 64 + ks * 16);
#pragma unroll
        for (int m = 0; m < 4; ++m)
#pragma unroll
            for (int n = 0; n < 4; ++n)
                acc[m][n] = __builtin_amdgcn_mfma_f32_16x16x32_f16(
                    af[m], bf[n], acc[m][n], 0, 0, 0);
    }
#pragma unroll
    for (int m = 0; m < 4; ++m) {
#pragma unroll
        for (int n = 0; n < 4; ++n) {
            int gn = n0 + 64 * wc + 16 * n + rl;
            float bv = bias[gn];
#pragma unroll
            for (int j = 0; j < 4; ++j) {
                int gm = m0 + 64 * wr + 16 * m + 4 * ks + j;
                float val = acc[m][n][j] + bv;
                if (MODE == 1) {
                    int s = gn >> 10, h = (gn >> 6) & 15, d = gn & 63;
                    int b2 = gm >> 13, ll = gm & 8191;
                    __half* dst = (s == 0) ? Q : (s == 1 ? Kb : Vb);
                    dst[(((size_t)(b2 * 16 + h) << 13) + ll) * 64 + d] = __float2half_rn(val);
                } else {
                    C[(size_t)gm * N + gn] = val;
                }
            }
        }
    }
}

// ---- fused attention: block-diagonal (256 keys) + sampled residual (256 keys,
// bias +log32, same-block masked) as ONE online softmax == reference LSE merge.
__global__ __launch_bounds__(256) void attn_kernel(
    const __half* __restrict__ q, const __half* __restrict__ k,
    const __half* __restrict__ v, const int* __restrict__ qidx,
    const int* __restrict__ kidx, const int* __restrict__ sampled,
    __half* __restrict__ pre)
{
    __shared__ float Ks[64][64];
    __shared__ float Vs[64][64];
    __shared__ int sblk[64];
    int bh = blockIdx.x >> 5, qb = blockIdx.x & 31;
    int bb = bh >> 4, hh = bh & 15;
    size_t hb = (size_t)bh << 13;
    int t = threadIdx.x;
    int dg = t & 3, qq = t >> 2;
    float qr[4][16], o[4][16], m[4], l[4];
    int origs[4];
#pragma unroll
    for (int i = 0; i < 4; ++i) {
        int s = qb * 256 + qq + 64 * i;
        int orig = qidx[hb + s];
        origs[i] = orig;
        load16h(q + (hb + orig) * 64 + dg * 16, qr[i]);
        m[i] = -1e30f; l[i] = 0.f;
#pragma unroll
        for (int w = 0; w < 16; ++w) o[i][w] = 0.f;
    }
    const float LOG32 = 3.4657359027997265f;
    for (int kc = 0; kc < 8; ++kc) {
        bool samp = kc >= 4;
        __syncthreads();
        {
            int j = t >> 2, c0 = (t & 3) * 16;
            int p = samp ? sampled[(size_t)bh * 256 + (kc - 4) * 64 + j]
                         : qb * 256 + kc * 64 + j;
            if (c0 == 0) sblk[j] = samp ? (p >> 8) : -1;
            int kr = kidx[hb + p];
            float kt[16], vt[16];
            load16h(k + (hb + kr) * 64 + c0, kt);
            load16h(v + (hb + kr) * 64 + c0, vt);
#pragma unroll
            for (int w = 0; w < 16; ++w) { Ks[j][c0 + w] = kt[w]; Vs[j][c0 + w] = vt[w]; }
        }
        __syncthreads();
        float badd = samp ? LOG32 : 0.f;
#pragma unroll 2
        for (int j = 0; j < 64; ++j) {
            if (sblk[j] == qb) continue;
            float kv16[16], vv16[16];
#pragma unroll
            for (int w = 0; w < 16; ++w) kv16[w] = Ks[j][dg * 16 + w];
#pragma unroll
            for (int w = 0; w < 16; ++w) vv16[w] = Vs[j][dg * 16 + w];
#pragma unroll
            for (int i = 0; i < 4; ++i) {
                float pp = 0.f;
#pragma unroll
                for (int w = 0; w < 16; ++w) pp += qr[i][w] * kv16[w];
                pp += __shfl_xor(pp, 1, 64);
                pp += __shfl_xor(pp, 2, 64);
                float sc = pp * 0.125f + badd;
                if (sc <= m[i]) {
                    float wg = __expf(sc - m[i]);
                    l[i] += wg;
#pragma unroll
                    for (int w = 0; w < 16; ++w) o[i][w] += wg * vv16[w];
                } else {
                    float fq = __expf(m[i] - sc);
                    m[i] = sc;
                    l[i] = l[i] * fq + 1.f;
#pragma unroll
                    for (int w = 0; w < 16; ++w) o[i][w] = o[i][w] * fq + vv16[w];
                }
            }
        }
    }
#pragma unroll
    for (int i = 0; i < 4; ++i) {
        float invl = 1.f / l[i];
        float res[16];
#pragma unroll
        for (int w = 0; w < 16; ++w) res[w] = o[i][w] * invl;
        store16h(pre + ((size_t)(bb * 8192 + origs[i]) * 1024) + hh * 64 + dg * 16, res);
    }
}

extern "C" void kernel_launch(void* const* d_in, const int* in_sizes, int n_in,
                              void* d_out, int out_size, void* d_ws, size_t ws_size,
                              hipStream_t stream)
{
    (void)in_sizes; (void)n_in; (void)out_size; (void)ws_size;
    const float* x     = (const float*)d_in[0];
    const float* Wqkv  = (const float*)d_in[1];
    const float* bqkv  = (const float*)d_in[2];
    const float* Wproj = (const float*)d_in[3];
    const float* bproj = (const float*)d_in[4];
    const float* proj  = (const float*)d_in[5];
    const int*   samp  = (const int*)d_in[6];
    float* out = (float*)d_out;

    char* ws = (char*)d_ws;
    size_t off = 0;
    auto take = [&](size_t bytes) {
        char* p = ws + off;
        off = (off + bytes + 255) & ~(size_t)255;
        return p;
    };
    _Float16* xh  = (_Float16*)take(33554432);   // x f16; REUSED as `pre` after QKV GEMM
    __half*   q   = (__half*)take(33554432);     // [B,H,L,64] f16
    __half*   k   = (__half*)take(33554432);
    __half*   v   = (__half*)take(33554432);
    _Float16* Wtq = (_Float16*)take(6291456);    // Wqkv^T f16 [3072][1024]
    _Float16* Wtp = (_Float16*)take(2097152);    // Wproj^T f16 [1024][1024]
    double* fold  = (double*)take(1835008);
    double* bfold = (double*)take(1792);
    int* hq   = (int*)take(1048576);
    int* hk   = (int*)take(1048576);
    int* qidx = (int*)take(1048576);
    int* kidx = (int*)take(1048576);
    __half* pre = (__half*)xh;                   // alias: xh dead after gemm_qkv
    // total ~148 MB

    fold_kernel<<<dim3(896), dim3(256), 0, stream>>>(Wqkv, bqkv, proj, fold, bfold);
    hash_kernel<<<dim3(32, 64), dim3(256), 0, stream>>>(x, fold, bfold, hq, hk);
    sort_kernel<<<dim3(64), dim3(256), 0, stream>>>(hq, hk, qidx, kidx);
    castx_kernel<<<dim3(16384), dim3(256), 0, stream>>>(x, xh);
    transpose_kernel<<<dim3(96, 32), dim3(256), 0, stream>>>(Wqkv, Wtq, 1024, 3072);
    transpose_kernel<<<dim3(32, 32), dim3(256), 0, stream>>>(Wproj, Wtp, 1024, 1024);
    mfma_gemm<1><<<dim3(24, 128), dim3(256), 0, stream>>>(
        xh, Wtq, bqkv, nullptr, q, k, v, 1024, 3072);
    attn_kernel<<<dim3(1024), dim3(256), 0, stream>>>(q, k, v, qidx, kidx, samp, pre);
    mfma_gemm<0><<<dim3(8, 128), dim3(256), 0, stream>>>(
        (const _Float16*)pre, Wtp, bproj, out, nullptr, nullptr, nullptr, 1024, 1024);
}

// Round 4
// 956.534 us; speedup vs baseline: 4.2593x; 1.7750x over previous
//
#include <hip/hip_runtime.h>
#include <hip/hip_fp16.h>
#include <math.h>

// Shapes (fixed): B=2, H=16, L=8192, dh=64, D=1024, 3*INNER=3072, NPROJ=7,
// BLOCK=256, SAMPLE=256.

typedef _Float16 f16x8 __attribute__((ext_vector_type(8)));
typedef _Float16 f16x4 __attribute__((ext_vector_type(4)));
typedef float f32x4 __attribute__((ext_vector_type(4)));

__device__ __forceinline__ void gl_lds16(const void* g, void* s) {
    __builtin_amdgcn_global_load_lds(
        (const __attribute__((address_space(1))) unsigned int*)g,
        (__attribute__((address_space(3))) unsigned int*)s, 16, 0, 0);
}

// ---- fold: fold[task*7168 + i*7 + r] = sum_d W[i, w*1024+h*64+d]*proj[d,r] (fp64) ----
__global__ __launch_bounds__(256) void fold_kernel(
    const float* __restrict__ W, const float* __restrict__ bias,
    const float* __restrict__ proj, double* __restrict__ fold,
    double* __restrict__ bfold)
{
    int idx = blockIdx.x * 256 + threadIdx.x;
    if (idx < 2 * 16 * 7 * 1024) {
        int task = idx / 7168;
        int rem = idx - task * 7168;
        int i = rem / 7;
        int r = rem - i * 7;
        int h = task & 15, w = task >> 4;
        double s = 0.0;
        const float* wp = W + (size_t)i * 3072 + w * 1024 + h * 64;
        for (int d = 0; d < 64; ++d)
            s += (double)wp[d] * (double)proj[d * 7 + r];
        fold[idx] = s;
    }
    if (idx < 224) {
        int r = idx % 7;
        int task = idx / 7;
        int h = task & 15, w = task >> 4;
        double s = 0.0;
        for (int d = 0; d < 64; ++d)
            s += (double)bias[w * 1024 + h * 64 + d] * (double)proj[d * 7 + r];
        bfold[idx] = s;
    }
}

// ---- hash: grid (task=32, rowblock=64); 256 rows x full K per block ----
__global__ __launch_bounds__(256) void hash_kernel(
    const float* __restrict__ x, const double* __restrict__ fold,
    const double* __restrict__ bfold, int* __restrict__ hq, int* __restrict__ hk)
{
    __shared__ __align__(16) float Xs[256][66];
    int task = blockIdx.x;
    int gr0 = blockIdx.y * 256;
    int t = threadIdx.x;
    const double* fbase = fold + (size_t)task * 7168;
    double acc[7] = {0, 0, 0, 0, 0, 0, 0};
    for (int c = 0; c < 16; ++c) {
        __syncthreads();
#pragma unroll
        for (int q2 = 0; q2 < 16; ++q2) {
            int fi = t + 256 * q2;
            int r2 = fi >> 4, c4 = fi & 15;
            float4 f = *(const float4*)&x[(size_t)(gr0 + r2) * 1024 + c * 64 + c4 * 4];
            *(float2*)&Xs[r2][c4 * 4] = make_float2(f.x, f.y);
            *(float2*)&Xs[r2][c4 * 4 + 2] = make_float2(f.z, f.w);
        }
        __syncthreads();
        const double* fc = fbase + c * 64 * 7;
#pragma unroll 4
        for (int i = 0; i < 64; ++i) {
            double xv = (double)Xs[t][i];
#pragma unroll
            for (int r = 0; r < 7; ++r)
                acc[r] = fma(xv, fc[i * 7 + r], acc[r]);
        }
    }
    int w = task >> 4, h = task & 15;
    int grow = gr0 + t;
    int b = grow >> 13, l = grow & 8191;
    int id = 0;
#pragma unroll
    for (int r = 0; r < 7; ++r)
        if (acc[r] + bfold[task * 7 + r] > 0.0) id |= (1 << r);
    int hsh = id ^ (id >> 1);
    (w ? hk : hq)[((size_t)(b * 16 + h) << 13) + l] = hsh;
}

// ---- stable counting sort (128 buckets) per (b,h) ----
__global__ __launch_bounds__(256) void sort_kernel(
    const int* __restrict__ hq, const int* __restrict__ hk,
    int* __restrict__ qidx, int* __restrict__ kidx)
{
    __shared__ unsigned short cnt[128][128];
    __shared__ int tot[128];
    __shared__ int base[128];
    int blk = blockIdx.x;
    int sel = blk >> 5, bh = blk & 31;
    const int* hp = (sel ? hk : hq) + ((size_t)bh << 13);
    int* op = (sel ? kidx : qidx) + ((size_t)bh << 13);
    int t = threadIdx.x;
    for (int i = t; i < 128 * 128 / 2; i += 256) ((unsigned int*)cnt)[i] = 0u;
    __syncthreads();
    if (t < 128) {
        const int* p = hp + t * 64;
        for (int j = 0; j < 64; ++j) cnt[t][p[j]]++;
    }
    __syncthreads();
    if (t < 128) {
        int run = 0;
        for (int c = 0; c < 128; ++c) {
            int x2 = cnt[c][t];
            cnt[c][t] = (unsigned short)run;
            run += x2;
        }
        tot[t] = run;
    }
    __syncthreads();
    if (t == 0) {
        int run = 0;
        for (int v = 0; v < 128; ++v) { base[v] = run; run += tot[v]; }
    }
    __syncthreads();
    if (t < 128) {
        const int* p = hp + t * 64;
        for (int j = 0; j < 64; ++j) {
            int v = p[j];
            int c = cnt[t][v];
            cnt[t][v] = (unsigned short)(c + 1);
            op[base[v] + c] = t * 64 + j;
        }
    }
}

// ---- cast x fp32 -> f16 ----
__global__ __launch_bounds__(256) void castx_kernel(
    const float* __restrict__ x, _Float16* __restrict__ xh)
{
    int i = blockIdx.x * 256 + threadIdx.x;
    float4 f = ((const float4*)x)[i];
    _Float16 h4[4] = {(_Float16)f.x, (_Float16)f.y, (_Float16)f.z, (_Float16)f.w};
    *(short4*)&xh[(size_t)i * 4] = *(short4*)h4;
}

// ---- transpose+cast: W[K][N] fp32 -> Wt[N][K] f16 ----
__global__ __launch_bounds__(256) void transpose_kernel(
    const float* __restrict__ W, _Float16* __restrict__ Wt, int K, int N)
{
    __shared__ float tile[32][33];
    int bx = blockIdx.x, by = blockIdx.y;
    int tx = threadIdx.x & 31, ty = threadIdx.x >> 5;
    for (int i = ty; i < 32; i += 8)
        tile[i][tx] = W[(size_t)(by * 32 + i) * N + bx * 32 + tx];
    __syncthreads();
    for (int i = ty; i < 32; i += 8)
        Wt[(size_t)(bx * 32 + i) * K + by * 32 + tx] = (_Float16)tile[tx][i];
}

// ---- f16 MFMA GEMM (m97 structure), from R3 (verified) ----
template <int MODE>
__global__ __launch_bounds__(256) void mfma_gemm(
    const _Float16* __restrict__ A, const _Float16* __restrict__ Bt,
    const float* __restrict__ bias, float* __restrict__ C,
    _Float16* __restrict__ Q, _Float16* __restrict__ Kb, _Float16* __restrict__ Vb,
    int K, int N)
{
    __shared__ __align__(16) _Float16 As[128 * 32];
    __shared__ __align__(16) _Float16 Bs[128 * 32];
    int t = threadIdx.x;
    int w = t >> 6, l = t & 63;
    int m0 = blockIdx.y * 128, n0 = blockIdx.x * 128;
    const _Float16* ga = A + (size_t)(m0 + 32 * w + (l >> 2)) * K + (l & 3) * 8;
    const _Float16* gb = Bt + (size_t)(n0 + 32 * w + (l >> 2)) * K + (l & 3) * 8;
    char* lasA = (char*)As + w * 2048;
    char* lasB = (char*)Bs + w * 2048;
    int wr = w >> 1, wc = w & 1;
    int rl = l & 15, ks = l >> 4;
    f32x4 acc[4][4];
#pragma unroll
    for (int m = 0; m < 4; ++m)
#pragma unroll
        for (int n = 0; n < 4; ++n) acc[m][n] = (f32x4){0.f, 0.f, 0.f, 0.f};
    for (int kk = 0; kk < K; kk += 32) {
        __syncthreads();
        gl_lds16(ga, lasA);
        gl_lds16(ga + 16 * K, lasA + 1024);
        gl_lds16(gb, lasB);
        gl_lds16(gb + 16 * K, lasB + 1024);
        ga += 32; gb += 32;
        __syncthreads();
        f16x8 af[4], bf[4];
#pragma unroll
        for (int m = 0; m < 4; ++m)
            af[m] = *(const f16x8*)((char*)As + (64 * wr + 16 * m + rl) * 64 + ks * 16);
#pragma unroll
        for (int n = 0; n < 4; ++n)
            bf[n] = *(const f16x8*)((char*)Bs + (64 * wc + 16 * n + rl) * 64 + ks * 16);
#pragma unroll
        for (int m = 0; m < 4; ++m)
#pragma unroll
            for (int n = 0; n < 4; ++n)
                acc[m][n] = __builtin_amdgcn_mfma_f32_16x16x32_f16(
                    af[m], bf[n], acc[m][n], 0, 0, 0);
    }
#pragma unroll
    for (int m = 0; m < 4; ++m) {
#pragma unroll
        for (int n = 0; n < 4; ++n) {
            int gn = n0 + 64 * wc + 16 * n + rl;
            float bv = bias[gn];
#pragma unroll
            for (int j = 0; j < 4; ++j) {
                int gm = m0 + 64 * wr + 16 * m + 4 * ks + j;
                float val = acc[m][n][j] + bv;
                if (MODE == 1) {
                    int s = gn >> 10, h = (gn >> 6) & 15, d = gn & 63;
                    int b2 = gm >> 13, ll = gm & 8191;
                    _Float16* dst = (s == 0) ? Q : (s == 1 ? Kb : Vb);
                    dst[(((size_t)(b2 * 16 + h) << 13) + ll) * 64 + d] = (_Float16)val;
                } else {
                    C[(size_t)gm * N + gn] = val;
                }
            }
        }
    }
}

// ---- MFMA fused attention.  grid (bh,qb)=1024, 4 waves x 64 queries.
// Swapped QK^T (S^T = K·Q^T, 16x16x32) -> online softmax with 2 shfl_xor
// -> PV as D^T = V^T·P^T (16x16x16; P^T already in B-frag layout, no shuffle).
// 8 key chunks of 64: c<4 block keys (bias 0), c>=4 sampled (bias +log32,
// masked when sampled block == qb).  == reference's LSE merge (R2-verified).
__global__ __launch_bounds__(256) void attn_mfma_kernel(
    const _Float16* __restrict__ q, const _Float16* __restrict__ k,
    const _Float16* __restrict__ v, const int* __restrict__ qidx,
    const int* __restrict__ kidx, const int* __restrict__ sampled,
    _Float16* __restrict__ pre)
{
    __shared__ __align__(16) _Float16 Vlds[64 * 64];  // XOR-swizzled row-major
    __shared__ int spos[64];
    int bh = blockIdx.x >> 5, qb = blockIdx.x & 31;
    int bb = bh >> 4, hh = bh & 15;
    size_t hb = (size_t)bh << 13;
    int t = threadIdx.x;
    int w = t >> 6, l = t & 63;
    int g = l >> 4, c16 = l & 15;
    int qw0 = qb * 256 + w * 64;

    // Q fragments (B-frag of swapped QK): lane holds Q[16n+c16][g*8..+7 (+32kc)]
    int orig[4];
    f16x8 qf[4][2];
#pragma unroll
    for (int n = 0; n < 4; ++n) {
        orig[n] = qidx[hb + qw0 + 16 * n + c16];
        const _Float16* qp = q + (hb + orig[n]) * 64 + g * 8;
        qf[n][0] = *(const f16x8*)(qp);
        qf[n][1] = *(const f16x8*)(qp + 32);
    }
    f32x4 o[4][4];     // [dblk][n]: D^T rows d=16dblk+4g+reg, col q=16n+c16
    float mr[4], lr[4];
#pragma unroll
    for (int n = 0; n < 4; ++n) {
        mr[n] = -1e30f; lr[n] = 0.f;
#pragma unroll
        for (int d2 = 0; d2 < 4; ++d2) o[d2][n] = (f32x4){0.f, 0.f, 0.f, 0.f};
    }
    const float LOG32 = 3.4657359027997265f;

    for (int c = 0; c < 8; ++c) {
        bool samp = c >= 4;
        __syncthreads();
        if (t < 64)
            spos[t] = samp ? sampled[(size_t)bh * 256 + (c - 4) * 64 + t]
                           : qb * 256 + c * 64 + t;
        {   // stage V[64 keys][64 dims] swizzled: byte ^= (row&7)<<4
            int kk = t >> 2;
            int p = samp ? sampled[(size_t)bh * 256 + (c - 4) * 64 + kk]
                         : qb * 256 + c * 64 + kk;
            int kr = kidx[hb + p];
            const _Float16* vp = v + (hb + kr) * 64;
            int d0 = (t & 3) * 16;
            f16x8 v0 = *(const f16x8*)(vp + d0);
            f16x8 v1 = *(const f16x8*)(vp + d0 + 8);
            int g0 = d0 >> 3;
            *(f16x8*)((char*)Vlds + kk * 128 + (((g0) ^ (kk & 7)) << 4)) = v0;
            *(f16x8*)((char*)Vlds + kk * 128 + (((g0 + 1) ^ (kk & 7)) << 4)) = v1;
        }
        __syncthreads();
        // S^T = K·Q^T
        f32x4 sacc[4][4];   // [m][n]: key=16m+4g+reg, q=16n+c16
#pragma unroll
        for (int m = 0; m < 4; ++m)
#pragma unroll
            for (int n = 0; n < 4; ++n) sacc[m][n] = (f32x4){0.f, 0.f, 0.f, 0.f};
#pragma unroll
        for (int m = 0; m < 4; ++m) {
            int p = spos[16 * m + c16];
            int kr = kidx[hb + p];
            const _Float16* kp = k + (hb + kr) * 64 + g * 8;
            f16x8 kf0 = *(const f16x8*)(kp);
            f16x8 kf1 = *(const f16x8*)(kp + 32);
#pragma unroll
            for (int n = 0; n < 4; ++n)
                sacc[m][n] = __builtin_amdgcn_mfma_f32_16x16x32_f16(
                    kf0, qf[n][0], sacc[m][n], 0, 0, 0);
#pragma unroll
            for (int n = 0; n < 4; ++n)
                sacc[m][n] = __builtin_amdgcn_mfma_f32_16x16x32_f16(
                    kf1, qf[n][1], sacc[m][n], 0, 0, 0);
        }
        // V^T A-frags from swizzled LDS (4x ds_read_u16 each; ~2-way, free)
        f16x4 av[4][4];   // [m][dblk]: A row d=16dblk+c16, k-elems key=16m+4g+j
#pragma unroll
        for (int m = 0; m < 4; ++m)
#pragma unroll
            for (int d2 = 0; d2 < 4; ++d2) {
                int d = 16 * d2 + c16;
#pragma unroll
                for (int j = 0; j < 4; ++j) {
                    int k2 = 16 * m + 4 * g + j;
                    av[m][d2][j] = *(const _Float16*)((char*)Vlds + k2 * 128 +
                        ((((d >> 3) ^ (k2 & 7)) << 4)) + (d & 7) * 2);
                }
            }
        // mask (sampled keys whose sorted block == qb)
        bool msk[4][4];   // [m][reg]
#pragma unroll
        for (int m = 0; m < 4; ++m)
#pragma unroll
            for (int r = 0; r < 4; ++r)
                msk[m][r] = samp && ((spos[16 * m + 4 * g + r] >> 8) == qb);
        float badd = samp ? LOG32 : 0.f;
        // online softmax + PV per query group n
#pragma unroll
        for (int n = 0; n < 4; ++n) {
            float sv[16];
#pragma unroll
            for (int m = 0; m < 4; ++m)
#pragma unroll
                for (int r = 0; r < 4; ++r)
                    sv[4 * m + r] = msk[m][r] ? -1e30f
                                  : sacc[m][n][r] * 0.125f + badd;
            float cm = sv[0];
#pragma unroll
            for (int r = 1; r < 16; ++r) cm = fmaxf(cm, sv[r]);
            cm = fmaxf(cm, __shfl_xor(cm, 16, 64));
            cm = fmaxf(cm, __shfl_xor(cm, 32, 64));
            float nm = fmaxf(mr[n], cm);
            float fq = __expf(mr[n] - nm);
            mr[n] = nm;
            float ps = 0.f;
            float pv16[16];
#pragma unroll
            for (int r = 0; r < 16; ++r) { pv16[r] = __expf(sv[r] - nm); ps += pv16[r]; }
            ps += __shfl_xor(ps, 16, 64);
            ps += __shfl_xor(ps, 32, 64);
            lr[n] = lr[n] * fq + ps;
#pragma unroll
            for (int d2 = 0; d2 < 4; ++d2) {
                o[d2][n][0] *= fq; o[d2][n][1] *= fq;
                o[d2][n][2] *= fq; o[d2][n][3] *= fq;
            }
            f16x4 pb[4];
#pragma unroll
            for (int m = 0; m < 4; ++m) {
                pb[m][0] = (_Float16)pv16[4 * m + 0];
                pb[m][1] = (_Float16)pv16[4 * m + 1];
                pb[m][2] = (_Float16)pv16[4 * m + 2];
                pb[m][3] = (_Float16)pv16[4 * m + 3];
            }
#pragma unroll
            for (int d2 = 0; d2 < 4; ++d2)
#pragma unroll
                for (int m = 0; m < 4; ++m)
                    o[d2][n] = __builtin_amdgcn_mfma_f32_16x16x16f16(
                        av[m][d2], pb[m], o[d2][n], 0, 0, 0);
        }
    }
    // store: lane holds 4 queries x 16 dims; 8B stores, rows coalesce in L2
#pragma unroll
    for (int n = 0; n < 4; ++n) {
        float invl = 1.f / lr[n];
        _Float16* pp = pre + ((size_t)(bb * 8192 + orig[n])) * 1024 + hh * 64;
#pragma unroll
        for (int d2 = 0; d2 < 4; ++d2) {
            f16x4 st;
            st[0] = (_Float16)(o[d2][n][0] * invl);
            st[1] = (_Float16)(o[d2][n][1] * invl);
            st[2] = (_Float16)(o[d2][n][2] * invl);
            st[3] = (_Float16)(o[d2][n][3] * invl);
            *(f16x4*)(pp + 16 * d2 + 4 * g) = st;
        }
    }
}

extern "C" void kernel_launch(void* const* d_in, const int* in_sizes, int n_in,
                              void* d_out, int out_size, void* d_ws, size_t ws_size,
                              hipStream_t stream)
{
    (void)in_sizes; (void)n_in; (void)out_size; (void)ws_size;
    const float* x     = (const float*)d_in[0];
    const float* Wqkv  = (const float*)d_in[1];
    const float* bqkv  = (const float*)d_in[2];
    const float* Wproj = (const float*)d_in[3];
    const float* bproj = (const float*)d_in[4];
    const float* proj  = (const float*)d_in[5];
    const int*   samp  = (const int*)d_in[6];
    float* out = (float*)d_out;

    char* ws = (char*)d_ws;
    size_t off = 0;
    auto take = [&](size_t bytes) {
        char* p = ws + off;
        off = (off + bytes + 255) & ~(size_t)255;
        return p;
    };
    _Float16* xh  = (_Float16*)take(33554432);   // x f16; reused as `pre`
    _Float16* q   = (_Float16*)take(33554432);   // [B,H,L,64] f16
    _Float16* k   = (_Float16*)take(33554432);
    _Float16* v   = (_Float16*)take(33554432);
    _Float16* Wtq = (_Float16*)take(6291456);
    _Float16* Wtp = (_Float16*)take(2097152);
    double* fold  = (double*)take(1835008);
    double* bfold = (double*)take(1792);
    int* hq   = (int*)take(1048576);
    int* hk   = (int*)take(1048576);
    int* qidx = (int*)take(1048576);
    int* kidx = (int*)take(1048576);
    _Float16* pre = xh;   // alias: xh dead after gemm_qkv

    fold_kernel<<<dim3(896), dim3(256), 0, stream>>>(Wqkv, bqkv, proj, fold, bfold);
    hash_kernel<<<dim3(32, 64), dim3(256), 0, stream>>>(x, fold, bfold, hq, hk);
    sort_kernel<<<dim3(64), dim3(256), 0, stream>>>(hq, hk, qidx, kidx);
    castx_kernel<<<dim3(16384), dim3(256), 0, stream>>>(x, xh);
    transpose_kernel<<<dim3(96, 32), dim3(256), 0, stream>>>(Wqkv, Wtq, 1024, 3072);
    transpose_kernel<<<dim3(32, 32), dim3(256), 0, stream>>>(Wproj, Wtp, 1024, 1024);
    mfma_gemm<1><<<dim3(24, 128), dim3(256), 0, stream>>>(
        xh, Wtq, bqkv, nullptr, q, k, v, 1024, 3072);
    attn_mfma_kernel<<<dim3(1024), dim3(256), 0, stream>>>(
        q, k, v, qidx, kidx, samp, pre);
    mfma_gemm<0><<<dim3(8, 128), dim3(256), 0, stream>>>(
        pre, Wtp, bproj, out, nullptr, nullptr, nullptr, 1024, 1024);
}